// Round 8
// baseline (269.548 us; speedup 1.0000x reference)
//
#include <hip/hip_runtime.h>
#include <cstddef>

static constexpr int Bb = 64;     // batch
static constexpr int Nn = 256;    // nodes
static constexpr int Td = 512;    // time dim
static constexpr int NMAXS = 51;  // 256 // 5
static constexpr float EPSN = 1e-5f;
static constexpr float EPSD = 1e-10f;

typedef unsigned short u16;
typedef __attribute__((ext_vector_type(8))) short short8;
typedef __attribute__((ext_vector_type(4))) float f32x4;

__device__ __forceinline__ u16 f2b(float f) {
    unsigned u = __float_as_uint(f);
    return (u16)((u + 0x7fffu + ((u >> 16) & 1u)) >> 16);
}
__device__ __forceinline__ float b2f(u16 h) {
    return __uint_as_float(((unsigned)h) << 16);
}
__device__ __forceinline__ float4 unp2(uint2 h, uint2 l) {
    float4 r;
    r.x = b2f((u16)h.x) + b2f((u16)l.x);
    r.y = b2f((u16)(h.x >> 16)) + b2f((u16)(l.x >> 16));
    r.z = b2f((u16)h.y) + b2f((u16)l.y);
    r.w = b2f((u16)(h.y >> 16)) + b2f((u16)(l.y >> 16));
    return r;
}

// async global->LDS DMA, 16B/lane. LDS dest = wave-uniform base + lane*16.
__device__ __forceinline__ void gload_lds(const u16* g, u16* l) {
    __builtin_amdgcn_global_load_lds(
        (const __attribute__((address_space(1))) unsigned int*)g,
        (__attribute__((address_space(3))) unsigned int*)l, 16, 0, 0);
}
__device__ __forceinline__ int swz4(int r) { return (r ^ (r >> 2)) & 3; }

// ---------------- LN stats stage A (z=0) + param prep (z=1) + bnacc zero ----------------
__global__ __launch_bounds__(256) void prep_ln_partial_k(const float4* __restrict__ x,
                                                         float2* __restrict__ part,
                                                         const float* __restrict__ cheb_w,
                                                         u16* __restrict__ bWc,
                                                         const float* __restrict__ li_w,
                                                         u16* __restrict__ liwhi,
                                                         u16* __restrict__ liwlo,
                                                         float* __restrict__ bnacc) {
    __shared__ float sh[256], sh2[256];
    __shared__ u16 tile[32][33];
    if (blockIdx.z == 0) {
        int b = blockIdx.y, c = blockIdx.x;
        int base = b * 32768 + c * 1024;
        float s = 0.f, s2 = 0.f;
#pragma unroll
        for (int j = 0; j < 4; ++j) {
            float4 v = x[base + j * 256 + threadIdx.x];
            s += v.x + v.y + v.z + v.w;
            s2 += v.x * v.x + v.y * v.y + v.z * v.z + v.w * v.w;
        }
        sh[threadIdx.x] = s; sh2[threadIdx.x] = s2;
        __syncthreads();
        for (int o = 128; o > 0; o >>= 1) {
            if (threadIdx.x < o) { sh[threadIdx.x] += sh[threadIdx.x + o]; sh2[threadIdx.x] += sh2[threadIdx.x + o]; }
            __syncthreads();
        }
        if (threadIdx.x == 0) part[b * 32 + c] = make_float2(sh[0], sh2[0]);
    } else {
        int lin = blockIdx.y * 32 + blockIdx.x;
        if (lin == 1024) {
            // zero BN accumulator (consumed by ln_apply's atomics next kernel)
            bnacc[threadIdx.x] = 0.f;
            bnacc[threadIdx.x + 256] = 0.f;
            return;
        }
        if (lin > 1024) return;
        int bx = lin & 15, by = (lin >> 4) & 15, bz = lin >> 8;
        int c0 = bx * 32, r0 = by * 32;
        int tx = threadIdx.x & 31, ty = threadIdx.x >> 5;
        if (bz < 3) {
            const float* ip = cheb_w + (size_t)bz * Td * Td;
#pragma unroll
            for (int i = 0; i < 4; ++i) {
                int r = ty + i * 8;
                tile[r][tx] = f2b(ip[(size_t)(r0 + r) * Td + c0 + tx]);
            }
            __syncthreads();
#pragma unroll
            for (int i = 0; i < 4; ++i) {
                int c = ty + i * 8;
                bWc[(size_t)(c0 + c) * 1536 + bz * 512 + (r0 + tx)] = tile[tx][c];
            }
        } else {
#pragma unroll
            for (int i = 0; i < 4; ++i) {
                int r = r0 + ty + i * 8;
                size_t idx = (size_t)r * Td + c0 + tx;
                float v = li_w[idx];
                u16 h = f2b(v);
                liwhi[idx] = h;
                liwlo[idx] = f2b(v - b2f(h));
            }
        }
    }
}

// LN apply: 1024-thread blocks, 4 x float4 per thread. LN-finalize runs ONCE per
// block (lanes 0-31 butterfly -> LDS broadcast). Each 32-lane half-wave covers
// exactly one (b,n) row -> BN stats via one 5-step butterfly + 1 atomic pair/row.
__global__ __launch_bounds__(1024) void ln_apply_split_k(const float4* __restrict__ x,
                                                         const float4* __restrict__ w,
                                                         const float4* __restrict__ bia,
                                                         const float2* __restrict__ part,
                                                         uint2* __restrict__ xhi,
                                                         uint2* __restrict__ xlo,
                                                         float* __restrict__ bnacc) {
    __shared__ float2 musd;
    int tid = threadIdx.x;
    int b = blockIdx.x >> 3;            // 8 blocks per batch (16384 floats each)
    if (tid < 32) {
        float2 p = part[b * 32 + tid];
        float s = p.x, s2 = p.y;
#pragma unroll
        for (int o = 16; o > 0; o >>= 1) { s += __shfl_xor(s, o, 32); s2 += __shfl_xor(s2, o, 32); }
        if (tid == 0) {
            float inv = 1.f / (Nn * Td);
            float mu = s * inv;
            float var = s2 * inv - mu * mu;
            musd = make_float2(mu, rsqrtf(var + EPSN));
        }
    }
    __syncthreads();
    float mu = musd.x, rs = musd.y;
    int i40 = blockIdx.x * 4096 + tid * 4;   // float4 index, 4 consecutive per thread
    float so = 0.f, so2 = 0.f;
#pragma unroll
    for (int j = 0; j < 4; ++j) {
        int i = i40 + j;
        int r = i & ((Nn * Td / 4) - 1);
        float4 xv = x[i], wv = w[r], bv = bia[r];
        float4 o;
        o.x = (xv.x - mu) * rs * wv.x + bv.x;
        o.y = (xv.y - mu) * rs * wv.y + bv.y;
        o.z = (xv.z - mu) * rs * wv.z + bv.z;
        o.w = (xv.w - mu) * rs * wv.w + bv.w;
        so += o.x + o.y + o.z + o.w;
        so2 += o.x * o.x + o.y * o.y + o.z * o.z + o.w * o.w;
        u16 hx = f2b(o.x), hy = f2b(o.y), hz = f2b(o.z), hw = f2b(o.w);
        uint2 ph, pl;
        ph.x = (unsigned)hx | ((unsigned)hy << 16);
        ph.y = (unsigned)hz | ((unsigned)hw << 16);
        pl.x = (unsigned)f2b(o.x - b2f(hx)) | ((unsigned)f2b(o.y - b2f(hy)) << 16);
        pl.y = (unsigned)f2b(o.z - b2f(hz)) | ((unsigned)f2b(o.w - b2f(hw)) << 16);
        xhi[i] = ph;
        xlo[i] = pl;
    }
    // 32-lane half-wave = one full (b,n) row of 512 floats
#pragma unroll
    for (int o = 16; o > 0; o >>= 1) { so += __shfl_xor(so, o); so2 += __shfl_xor(so2, o); }
    if ((tid & 31) == 0) {
        int n = (i40 >> 7) & 255;        // row = float4_idx / 128
        atomicAdd(&bnacc[2 * n], so);
        atomicAdd(&bnacc[2 * n + 1], so2);
    }
}

// ---------------- top-k: wave-per-row radix select, zero __syncthreads ----------------
__global__ __launch_bounds__(256) void topk_sel_k(const float4* __restrict__ sc4,
                                                  const float4* __restrict__ dis4,
                                                  uint2* __restrict__ bA2,
                                                  float* __restrict__ dinv) {
    __shared__ int hist[4][256];
    __shared__ int2 pr[4];
    int tid = threadIdx.x, lane = tid & 63, wv = tid >> 6;
    int row = blockIdx.x * 4 + wv;
    int n = row & 255;
    float4 v = sc4[(size_t)row * 64 + lane];
    float vv[4] = { v.x, v.y, v.z, v.w };
    unsigned key[4];
#pragma unroll
    for (int j = 0; j < 4; ++j) {
        unsigned fu = __float_as_uint(vv[j]);
        key[j] = (fu & 0x80000000u) ? ~fu : (fu | 0x80000000u);
    }
    unsigned pref = 0u;
    int rank = Nn - NMAXS;   // 205
#pragma unroll
    for (int shift = 24; shift >= 0; shift -= 8) {
        unsigned mhi = (shift == 24) ? 0u : (0xFFFFFFFFu << (shift + 8));
        *(int4*)&hist[wv][lane * 4] = make_int4(0, 0, 0, 0);
        __threadfence_block();
#pragma unroll
        for (int j = 0; j < 4; ++j)
            if ((key[j] & mhi) == pref) atomicAdd(&hist[wv][(key[j] >> shift) & 255], 1);
        __threadfence_block();
        int4 h = *(const int4*)&hist[wv][lane * 4];
        int s0 = h.x, s1 = s0 + h.y, s2 = s1 + h.z, s3 = s2 + h.w;
        int t = s3;
#pragma unroll
        for (int o = 1; o < 64; o <<= 1) { int y = __shfl_up(t, o, 64); if (lane >= o) t += y; }
        int excl = t - s3;
        int below[4] = { excl, excl + s0, excl + s1, excl + s2 };
        int cum[4]   = { excl + s0, excl + s1, excl + s2, excl + s3 };
#pragma unroll
        for (int j = 0; j < 4; ++j) {
            if (cum[j] > rank && below[j] <= rank)
                pr[wv] = make_int2((int)(pref | ((unsigned)(lane * 4 + j) << shift)), rank - below[j]);
        }
        __threadfence_block();
        int2 p = pr[wv];
        pref = (unsigned)p.x;
        rank = p.y;
    }
    float kth = __uint_as_float((pref & 0x80000000u) ? (pref & 0x7FFFFFFFu) : ~pref);
    float4 dv = dis4[(size_t)n * 64 + lane];
    float dd[4] = { dv.x, dv.y, dv.z, dv.w };
    float s = 0.f;
    u16 o16[4];
#pragma unroll
    for (int j = 0; j < 4; ++j) {
        float as = (vv[j] >= kth) ? vv[j] : 0.f;
        float a = fmaxf(as + dd[j], 0.f);
        o16[j] = f2b(a);
        s += a;
    }
    uint2 ow;
    ow.x = (unsigned)o16[0] | ((unsigned)o16[1] << 16);
    ow.y = (unsigned)o16[2] | ((unsigned)o16[3] << 16);
    bA2[(size_t)row * 64 + lane] = ow;
#pragma unroll
    for (int o = 32; o > 0; o >>= 1) s += __shfl_down(s, o, 64);
    if (lane == 0) dinv[row] = rsqrtf(s + EPSD);
}

// ---------------- fused BN-apply + full Chebyshev recursion (Tx0, Tx1, Tx2) ----------------
// Block = (t-slice of 128 cols, batch). 512 threads / 8 waves (4 row-groups x 2 col-groups).
// Zt[128 t][256 m] bf16 stays LDS-resident; A streamed twice with double-buffered DMA.
__global__ __launch_bounds__(512) void cheb_fused_k(const uint2* __restrict__ xhi,
                                                    const uint2* __restrict__ xlo,
                                                    const float* __restrict__ bnacc,
                                                    const float* __restrict__ g,
                                                    const float* __restrict__ be,
                                                    const float* __restrict__ dinv,
                                                    const u16* __restrict__ bA,
                                                    u16* __restrict__ cat) {
    __shared__ u16 Zt[128 * 256];          // 64KB  [t][m-chunk swizzled]
    __shared__ u16 As[2][2][256 * 32];     // 64KB  [buf][half][row*32 + chunk]
    __shared__ float scl[256], sft[256], dvv[256];
    int z = blockIdx.y, tb = blockIdx.x;   // tb in [0,4): 128-col t-slice
    int tid = threadIdx.x, lane = tid & 63, wave = tid >> 6;
    const u16* Ab = bA + (size_t)z * (Nn * Nn);
    int wr = (wave >> 1) * 64, wc = (wave & 1) * 64;
    int fr = lane & 15, fq = lane >> 4;

    // phase 0: per-node BN scale/shift + dinv into LDS
    if (tid < 256) {
        const float inv = 1.f / (Bb * Td);
        float s = bnacc[2 * tid], s2 = bnacc[2 * tid + 1];
        float mu = s * inv;
        float var = s2 * inv - mu * mu;
        float rs = rsqrtf(var + EPSN);
        float sc_ = rs * g[tid];
        scl[tid] = sc_;
        sft[tid] = be[tid] - mu * sc_;
        dvv[tid] = dinv[z * 256 + tid];
    }
    __syncthreads();

    auto stageA = [&](int buf, int k0) {
#pragma unroll
        for (int h = 0; h < 2; ++h) {
#pragma unroll
            for (int sub = 0; sub < 2; ++sub) {
                int r = wave * 32 + sub * 16 + (lane >> 2);
                int kc = ((lane & 3) ^ swz4(r)) << 3;
                gload_lds(Ab + (size_t)r * 256 + k0 + h * 32 + kc,
                          &As[buf][h][(wave * 32 + sub * 16) * 32]);
            }
        }
    };

    f32x4 acc[4][4] = {};
    auto compute = [&](int buf, int kk) {
#pragma unroll
        for (int h = 0; h < 2; ++h) {
            short8 af[4], bf[4];
#pragma unroll
            for (int mi = 0; mi < 4; ++mi) {
                int rr = wr + mi * 16 + fr;
                af[mi] = *(const short8*)&As[buf][h][rr * 32 + ((fq ^ swz4(rr)) << 3)];
            }
            int c5 = ((kk + h * 32) >> 3) + fq;
#pragma unroll
            for (int ni = 0; ni < 4; ++ni) {
                int cc = wc + ni * 16 + fr;
                bf[ni] = *(const short8*)&Zt[cc * 256 + ((c5 ^ (cc & 31)) << 3)];
            }
#pragma unroll
            for (int mi = 0; mi < 4; ++mi)
#pragma unroll
                for (int ni = 0; ni < 4; ++ni)
                    acc[mi][ni] = __builtin_amdgcn_mfma_f32_16x16x32_bf16(af[mi], bf[ni], acc[mi][ni], 0, 0, 0);
        }
    };

    // issue GEMM1 step-0 DMA; it lands during Z-build
    stageA(0, 0);

    // Z-build: BN apply -> write cat Tx0 (global) + Z0 = dv*Tx0 (LDS, transposed)
    {
        int mrow = tid >> 5;            // 16 rows per pass
        int c = tid & 31;               // uint2 col within 32 (4 t each)
        int t4g0 = tb * 32;
#pragma unroll 4
        for (int p = 0; p < 16; ++p) {
            int m = p * 16 + mrow;
            size_t idx = ((size_t)(z * 256 + m)) * 128 + t4g0 + c;
            float4 v = unp2(xhi[idx], xlo[idx]);
            float sc_ = scl[m], sh_ = sft[m], dv = dvv[m];
            v.x = v.x * sc_ + sh_; v.y = v.y * sc_ + sh_;
            v.z = v.z * sc_ + sh_; v.w = v.w * sc_ + sh_;
            uint2 o2;
            o2.x = (unsigned)f2b(v.x) | ((unsigned)f2b(v.y) << 16);
            o2.y = (unsigned)f2b(v.z) | ((unsigned)f2b(v.w) << 16);
            *(uint2*)&cat[((size_t)(z * 256 + m)) * 1536 + (size_t)(t4g0 + c) * 4] = o2;
            u16 zv[4] = { f2b(v.x * dv), f2b(v.y * dv), f2b(v.z * dv), f2b(v.w * dv) };
#pragma unroll
            for (int j = 0; j < 4; ++j) {
                int tl = c * 4 + j;     // local t in [0,128)
                Zt[tl * 256 + (((m >> 3) ^ (tl & 31)) << 3) + (m & 7)] = zv[j];
            }
        }
    }
    __syncthreads();   // Z0 visible + GEMM1 step-0 DMA drained

    // GEMM1: Y1 = A @ Z0   (K=256, 4 steps of 64)
    for (int s = 0; s < 4; ++s) {
        if (s < 3) stageA((s + 1) & 1, (s + 1) * 64);
        compute(s & 1, s * 64);
        __syncthreads();
    }

    // prefetch GEMM2 step-0 (overlaps epilogue-1)
    stageA(0, 0);

    // epilogue 1: Tx1 = dv[n]*Y1 -> cat[.,512:1024]; Z1 = dv[n]*Tx1 -> Zt
#pragma unroll
    for (int mi = 0; mi < 4; ++mi) {
#pragma unroll
        for (int rg = 0; rg < 4; ++rg) {
            int n = wr + mi * 16 + fq * 4 + rg;
            float dv = dvv[n];
            size_t rowb = (size_t)(z * 256 + n) * 1536;
#pragma unroll
            for (int ni = 0; ni < 4; ++ni) {
                int tl = wc + ni * 16 + fr;
                float tx1 = dv * acc[mi][ni][rg];
                cat[rowb + 512 + tb * 128 + tl] = f2b(tx1);
                Zt[tl * 256 + (((n >> 3) ^ (tl & 31)) << 3) + (n & 7)] = f2b(dv * tx1);
            }
            acc[mi][0][rg] = 0.f; acc[mi][1][rg] = 0.f;
            acc[mi][2][rg] = 0.f; acc[mi][3][rg] = 0.f;
        }
    }
    __syncthreads();   // Z1 visible + GEMM2 step-0 DMA drained

    // GEMM2: Y2 = A @ Z1
    for (int s = 0; s < 4; ++s) {
        if (s < 3) stageA((s + 1) & 1, (s + 1) * 64);
        compute(s & 1, s * 64);
        if (s < 3) __syncthreads();
    }

    // epilogue 2: Tx2 = 2*dv[n]*Y2 - Tx0 -> cat[.,1024:1536]  (Tx0 read back, L2-hot)
    __threadfence_block();
#pragma unroll
    for (int mi = 0; mi < 4; ++mi) {
#pragma unroll
        for (int rg = 0; rg < 4; ++rg) {
            int n = wr + mi * 16 + fq * 4 + rg;
            float dv2 = 2.f * dvv[n];
            size_t rowb = (size_t)(z * 256 + n) * 1536;
#pragma unroll
            for (int ni = 0; ni < 4; ++ni) {
                int tg = tb * 128 + wc + ni * 16 + fr;
                float v = dv2 * acc[mi][ni][rg] - b2f(cat[rowb + tg]);
                cat[rowb + 1024 + tg] = f2b(v);
            }
        }
    }
}

// ---------------- bf16 MFMA GEMM, NT: tile 64(M)x128(N), BK=32, 2-buf ----------------
// Grid-split fix: 64-row tiles double the grid to 1024 blocks = 4 blocks/CU
// (vs 128x128's 512 = 2/CU grid cap) -> 4 waves/SIMD; cross-block overlap hides
// the per-iter DMA drain. 24KB LDS, acc[2][4]. Same K-order -> bit-identical.
template <bool FINAL, bool WF32>
__global__ __launch_bounds__(256) void gemm_bf_k(const u16* __restrict__ A,
                                                 const u16* __restrict__ Bt,
                                                 const float* __restrict__ bias,
                                                 float* __restrict__ C,
                                                 int Ncols, int K) {
    __shared__ u16 As[2][2048];   // [buf][64 rows * 32]
    __shared__ u16 Bs[2][4096];   // [buf][128 rows * 32]
    int br = blockIdx.x * 64, bc = blockIdx.y * 128;
    int tid = threadIdx.x, lane = tid & 63, wave = tid >> 6;
    int wr = (wave >> 1) * 32, wc = (wave & 1) * 64;   // wave = 32 rows x 64 cols
    int lr = lane >> 2, lc = lane & 3;
    int rA = wave * 16 + lr;            // A rows 0..63
    const u16* gA = A + (size_t)(br + rA) * K + (((lc ^ swz4(rA)) << 3));
    int rB0 = wave * 16 + lr;           // B rows 0..63
    int rB1 = 64 + rB0;                 // B rows 64..127
    const u16* gB0 = Bt + (size_t)(bc + rB0) * K + (((lc ^ swz4(rB0)) << 3));
    const u16* gB1 = Bt + (size_t)(bc + rB1) * K + (((lc ^ swz4(rB1)) << 3));
    f32x4 acc[2][4] = {};
    int fr = lane & 15, fq = lane >> 4;
    auto stage = [&](int buf, int k0) {
        gload_lds(gA + k0, &As[buf][wave * 512]);
        gload_lds(gB0 + k0, &Bs[buf][wave * 512]);
        gload_lds(gB1 + k0, &Bs[buf][2048 + wave * 512]);
    };
    int nIter = K >> 5;                 // 48 for K=1536
    stage(0, 0);
    for (int it = 0; it < nIter; ++it) {
        int cur = it & 1;
        __syncthreads();                // drains stage(cur) issued one iter ago
        if (it + 1 < nIter) stage(1 - cur, (it + 1) << 5);
        short8 af[2], bf[4];
#pragma unroll
        for (int mi = 0; mi < 2; ++mi) {
            int rr = wr + mi * 16 + fr;
            af[mi] = *(const short8*)&As[cur][rr * 32 + ((fq ^ swz4(rr)) << 3)];
        }
#pragma unroll
        for (int ni = 0; ni < 4; ++ni) {
            int rr = wc + ni * 16 + fr;
            bf[ni] = *(const short8*)&Bs[cur][rr * 32 + ((fq ^ swz4(rr)) << 3)];
        }
#pragma unroll
        for (int mi = 0; mi < 2; ++mi)
#pragma unroll
            for (int ni = 0; ni < 4; ++ni)
                acc[mi][ni] = __builtin_amdgcn_mfma_f32_16x16x32_bf16(af[mi], bf[ni], acc[mi][ni], 0, 0, 0);
    }
#pragma unroll
    for (int mi = 0; mi < 2; ++mi) {
#pragma unroll
        for (int rg = 0; rg < 4; ++rg) {
            int row = br + wr + mi * 16 + fq * 4 + rg;
#pragma unroll
            for (int ni = 0; ni < 4; ++ni) {
                int col = bc + wc + ni * 16 + fr;
                float v = acc[mi][ni][rg];
                if (FINAL) v = fmaxf(v + bias[col], 0.f);
                if (WF32) C[(size_t)row * Ncols + col] = v;
            }
        }
    }
}

// ---------------- split-bf16 3-MFMA GEMM, NT, DMA + double-buffered prefetch, BK=32 ----------------
template <bool BIAS, bool WSPLIT, bool WF32>
__global__ __launch_bounds__(256) void gemm_bf3_k(const u16* __restrict__ Ahi,
                                                  const u16* __restrict__ Alo,
                                                  const u16* __restrict__ Bhi,
                                                  const u16* __restrict__ Blo,
                                                  const float* __restrict__ bias,
                                                  float* __restrict__ C,
                                                  u16* __restrict__ Chi,
                                                  u16* __restrict__ Clo,
                                                  int Ncols, int K,
                                                  long long sA, long long sB, long long sC) {
    __shared__ u16 Ash[2][4096];
    __shared__ u16 Asl[2][4096];
    __shared__ u16 Bsh[2][4096];
    __shared__ u16 Bsl[2][4096];
    int z = blockIdx.z;
    const u16* Agh = Ahi + (size_t)z * sA;
    const u16* Agl = Alo + (size_t)z * sA;
    const u16* Bgh = Bhi + (size_t)z * sB;
    const u16* Bgl = Blo + (size_t)z * sB;
    int br = blockIdx.x * 128, bc = blockIdx.y * 128;
    int tid = threadIdx.x, lane = tid & 63, wave = tid >> 6;
    int wr = (wave >> 1) * 64, wc = (wave & 1) * 64;
    int i0 = wave * 2;
    int rl0 = i0 * 16 + (lane >> 2);
    int rl1 = rl0 + 16;
    int cp = lane & 3;
    int ca0 = (cp ^ swz4(rl0)) * 8;
    int ca1 = (cp ^ swz4(rl1)) * 8;
    size_t oA0 = (size_t)(br + rl0) * K + ca0;
    size_t oA1 = (size_t)(br + rl1) * K + ca1;
    size_t oB0 = (size_t)(bc + rl0) * K + ca0;
    size_t oB1 = (size_t)(bc + rl1) * K + ca1;
    f32x4 acc[4][4] = {};
    int fr = lane & 15, fq = lane >> 4;
    auto stage = [&](int buf, int kk) {
        gload_lds(Agh + oA0 + kk, &Ash[buf][i0 * 512]);
        gload_lds(Agh + oA1 + kk, &Ash[buf][i0 * 512 + 512]);
        gload_lds(Agl + oA0 + kk, &Asl[buf][i0 * 512]);
        gload_lds(Agl + oA1 + kk, &Asl[buf][i0 * 512 + 512]);
        gload_lds(Bgh + oB0 + kk, &Bsh[buf][i0 * 512]);
        gload_lds(Bgh + oB1 + kk, &Bsh[buf][i0 * 512 + 512]);
        gload_lds(Bgl + oB0 + kk, &Bsl[buf][i0 * 512]);
        gload_lds(Bgl + oB1 + kk, &Bsl[buf][i0 * 512 + 512]);
    };
    int nIter = K >> 5;
    stage(0, 0);
    for (int it = 0; it < nIter; ++it) {
        int cur = it & 1;
        __syncthreads();
        if (it + 1 < nIter) stage(1 - cur, (it + 1) << 5);
        short8 afh[4], afl[4], bfh[4], bfl[4];
#pragma unroll
        for (int mi = 0; mi < 4; ++mi) {
            int rr = wr + mi * 16 + fr;
            int off = rr * 32 + ((fq ^ swz4(rr)) << 3);
            afh[mi] = *(const short8*)&Ash[cur][off];
            afl[mi] = *(const short8*)&Asl[cur][off];
        }
#pragma unroll
        for (int ni = 0; ni < 4; ++ni) {
            int rr = wc + ni * 16 + fr;
            int off = rr * 32 + ((fq ^ swz4(rr)) << 3);
            bfh[ni] = *(const short8*)&Bsh[cur][off];
            bfl[ni] = *(const short8*)&Bsl[cur][off];
        }
#pragma unroll
        for (int mi = 0; mi < 4; ++mi)
#pragma unroll
            for (int ni = 0; ni < 4; ++ni) {
                acc[mi][ni] = __builtin_amdgcn_mfma_f32_16x16x32_bf16(afh[mi], bfh[ni], acc[mi][ni], 0, 0, 0);
                acc[mi][ni] = __builtin_amdgcn_mfma_f32_16x16x32_bf16(afh[mi], bfl[ni], acc[mi][ni], 0, 0, 0);
                acc[mi][ni] = __builtin_amdgcn_mfma_f32_16x16x32_bf16(afl[mi], bfh[ni], acc[mi][ni], 0, 0, 0);
            }
    }
    float* Cp = WF32 ? C + (size_t)z * sC : nullptr;
    u16* Chp = WSPLIT ? Chi + (size_t)z * sC : nullptr;
    u16* Clp = WSPLIT ? Clo + (size_t)z * sC : nullptr;
#pragma unroll
    for (int mi = 0; mi < 4; ++mi) {
#pragma unroll
        for (int rg = 0; rg < 4; ++rg) {
            int row = br + wr + mi * 16 + fq * 4 + rg;
            size_t rb = (size_t)row * Ncols;
#pragma unroll
            for (int ni = 0; ni < 4; ++ni) {
                int col = bc + wc + ni * 16 + fr;
                float v = acc[mi][ni][rg];
                if (BIAS) v += bias[col];
                if (WF32) Cp[rb + col] = v;
                if (WSPLIT) {
                    u16 h = f2b(v);
                    Chp[rb + col] = h;
                    Clp[rb + col] = f2b(v - b2f(h));
                }
            }
        }
    }
}

extern "C" void kernel_launch(void* const* d_in, const int* in_sizes, int n_in,
                              void* d_out, int out_size, void* d_ws, size_t ws_size,
                              hipStream_t stream) {
    const float* x      = (const float*)d_in[0];
    const float* dis    = (const float*)d_in[1];
    const float* ln_w   = (const float*)d_in[2];
    const float* ln_b   = (const float*)d_in[3];
    const float* bn_g   = (const float*)d_in[4];
    const float* bn_b   = (const float*)d_in[5];
    const float* li_w   = (const float*)d_in[6];
    const float* li_b   = (const float*)d_in[7];
    const float* cheb_w = (const float*)d_in[8];
    const float* cheb_b = (const float*)d_in[9];
    float* out = (float*)d_out;

    const size_t BNT = (size_t)Bb * Nn * Td;   // 8388608
    const size_t BNN = (size_t)Bb * Nn * Nn;   // 4194304
    float* ws = (float*)d_ws;
    u16* xhi = (u16*)ws;
    u16* xlo = xhi + BNT;
    u16* xphi = (u16*)(ws + BNT);
    u16* xplo = xphi + BNT;
    u16* cat  = (u16*)(ws + BNT);               // [16384][1536] bf16 (reuses xp region after scores)
    float* sc = ws + 2 * BNT;
    float* p4 = ws + 2 * BNT + BNN;
    float* p5 = p4 + BNT / 2;
    u16* bA = (u16*)p5;                          // BNN u16
    float* p6 = p5 + BNN / 2;
    u16* bWc = (u16*)p6;                         // 512*1536 u16
    float* p7 = p6 + (512 * 1536) / 2;
    u16* liwhi = (u16*)p7;                       // 512*512 u16 x2
    u16* liwlo = liwhi + 512 * 512;
    float* p8 = p7 + 262144;
    float* dinv = p8;                            // 16384
    float2* part = (float2*)(dinv + 16384);      // 2048 float2
    float* bnacc = (float*)(part + 2048);        // 512 floats (BN sum/sumsq accum)

    // 1. LN stage A + param prep + bnacc zero (one launch, grid-z split)
    hipLaunchKernelGGL(prep_ln_partial_k, dim3(32, Bb, 2), dim3(256), 0, stream,
                       (const float4*)x, part, cheb_w, bWc, li_w, liwhi, liwlo, bnacc);
    // 2. LN apply (block-wide finalize broadcast) -> hi/lo split; BN stats via atomics
    hipLaunchKernelGGL(ln_apply_split_k, dim3(BNT / 16384), dim3(1024), 0, stream,
                       (const float4*)x, (const float4*)ln_w, (const float4*)ln_b, part,
                       (uint2*)xhi, (uint2*)xlo, bnacc);
    // 3. xp = x_ln @ li_w^T + li_b  (split-bf16 3-MFMA -> hi/lo)
    hipLaunchKernelGGL((gemm_bf3_k<true, true, false>), dim3(Bb * Nn / 128, Td / 128, 1), dim3(256), 0, stream,
                       xhi, xlo, liwhi, liwlo, li_b, (float*)nullptr, xphi, xplo,
                       Td, Td, 0LL, 0LL, 0LL);
    // 4. scores[b] = xp[b] @ xp[b]^T  (split-bf16 -> fp32)
    hipLaunchKernelGGL((gemm_bf3_k<false, false, true>), dim3(Nn / 128, Nn / 128, Bb), dim3(256), 0, stream,
                       xphi, xplo, xphi, xplo, (const float*)nullptr, sc, (u16*)nullptr, (u16*)nullptr,
                       Nn, Td, (long long)Nn * Td, (long long)Nn * Td, (long long)Nn * Nn);
    // 5. top-k wave-per-row radix select; A = relu(A_s + dis) -> bf16 bA; dinv
    hipLaunchKernelGGL(topk_sel_k, dim3(Bb * Nn / 4), dim3(256), 0, stream,
                       (const float4*)sc, (const float4*)dis, (uint2*)bA, dinv);
    // 6. fused BN-apply + Chebyshev (512 thr / 8 waves): writes cat Tx0|Tx1|Tx2
    hipLaunchKernelGGL(cheb_fused_k, dim3(Td / 128, Bb), dim3(512), 0, stream,
                       (const uint2*)xhi, (const uint2*)xlo, bnacc, bn_g, bn_b,
                       dinv, bA, cat);
    // 7. out = relu([Tx0|Tx1|Tx2] @ [W0;W1;W2]^T + cheb_b)  (K=1536, 64x128 tile, 1024 blocks)
    hipLaunchKernelGGL((gemm_bf_k<true, true>), dim3(Bb * Nn / 64, Td / 128, 1), dim3(256), 0, stream,
                       cat, bWc, cheb_b, out, Td, 1536);
}

// Round 9
// 266.181 us; speedup vs baseline: 1.0127x; 1.0127x over previous
//
#include <hip/hip_runtime.h>
#include <cstddef>

static constexpr int Bb = 64;     // batch
static constexpr int Nn = 256;    // nodes
static constexpr int Td = 512;    // time dim
static constexpr int NMAXS = 51;  // 256 // 5
static constexpr float EPSN = 1e-5f;
static constexpr float EPSD = 1e-10f;

typedef unsigned short u16;
typedef __attribute__((ext_vector_type(8))) short short8;
typedef __attribute__((ext_vector_type(4))) float f32x4;

__device__ __forceinline__ u16 f2b(float f) {
    unsigned u = __float_as_uint(f);
    return (u16)((u + 0x7fffu + ((u >> 16) & 1u)) >> 16);
}
__device__ __forceinline__ float b2f(u16 h) {
    return __uint_as_float(((unsigned)h) << 16);
}
__device__ __forceinline__ float4 unp2(uint2 h, uint2 l) {
    float4 r;
    r.x = b2f((u16)h.x) + b2f((u16)l.x);
    r.y = b2f((u16)(h.x >> 16)) + b2f((u16)(l.x >> 16));
    r.z = b2f((u16)h.y) + b2f((u16)l.y);
    r.w = b2f((u16)(h.y >> 16)) + b2f((u16)(l.y >> 16));
    return r;
}

// async global->LDS DMA, 16B/lane. LDS dest = wave-uniform base + lane*16.
__device__ __forceinline__ void gload_lds(const u16* g, u16* l) {
    __builtin_amdgcn_global_load_lds(
        (const __attribute__((address_space(1))) unsigned int*)g,
        (__attribute__((address_space(3))) unsigned int*)l, 16, 0, 0);
}
__device__ __forceinline__ int swz4(int r) { return (r ^ (r >> 2)) & 3; }

// ---------------- LN stats stage A (z=0) + param prep (z=1) + bnacc zero ----------------
__global__ __launch_bounds__(256) void prep_ln_partial_k(const float4* __restrict__ x,
                                                         float2* __restrict__ part,
                                                         const float* __restrict__ cheb_w,
                                                         u16* __restrict__ bWc,
                                                         const float* __restrict__ li_w,
                                                         u16* __restrict__ liwhi,
                                                         u16* __restrict__ liwlo,
                                                         float* __restrict__ bnacc) {
    __shared__ float sh[256], sh2[256];
    __shared__ u16 tile[32][33];
    if (blockIdx.z == 0) {
        int b = blockIdx.y, c = blockIdx.x;
        int base = b * 32768 + c * 1024;
        float s = 0.f, s2 = 0.f;
#pragma unroll
        for (int j = 0; j < 4; ++j) {
            float4 v = x[base + j * 256 + threadIdx.x];
            s += v.x + v.y + v.z + v.w;
            s2 += v.x * v.x + v.y * v.y + v.z * v.z + v.w * v.w;
        }
        sh[threadIdx.x] = s; sh2[threadIdx.x] = s2;
        __syncthreads();
        for (int o = 128; o > 0; o >>= 1) {
            if (threadIdx.x < o) { sh[threadIdx.x] += sh[threadIdx.x + o]; sh2[threadIdx.x] += sh2[threadIdx.x + o]; }
            __syncthreads();
        }
        if (threadIdx.x == 0) part[b * 32 + c] = make_float2(sh[0], sh2[0]);
    } else {
        int lin = blockIdx.y * 32 + blockIdx.x;
        if (lin == 1024) {
            // zero BN accumulator (consumed by ln_apply's atomics next kernel)
            bnacc[threadIdx.x] = 0.f;
            bnacc[threadIdx.x + 256] = 0.f;
            return;
        }
        if (lin > 1024) return;
        int bx = lin & 15, by = (lin >> 4) & 15, bz = lin >> 8;
        int c0 = bx * 32, r0 = by * 32;
        int tx = threadIdx.x & 31, ty = threadIdx.x >> 5;
        if (bz < 3) {
            const float* ip = cheb_w + (size_t)bz * Td * Td;
#pragma unroll
            for (int i = 0; i < 4; ++i) {
                int r = ty + i * 8;
                tile[r][tx] = f2b(ip[(size_t)(r0 + r) * Td + c0 + tx]);
            }
            __syncthreads();
#pragma unroll
            for (int i = 0; i < 4; ++i) {
                int c = ty + i * 8;
                bWc[(size_t)(c0 + c) * 1536 + bz * 512 + (r0 + tx)] = tile[tx][c];
            }
        } else {
#pragma unroll
            for (int i = 0; i < 4; ++i) {
                int r = r0 + ty + i * 8;
                size_t idx = (size_t)r * Td + c0 + tx;
                float v = li_w[idx];
                u16 h = f2b(v);
                liwhi[idx] = h;
                liwlo[idx] = f2b(v - b2f(h));
            }
        }
    }
}

// LN apply: 1024-thread blocks, 4 x float4 per thread. LN-finalize runs ONCE per
// block (lanes 0-31 butterfly -> LDS broadcast). Each 32-lane half-wave covers
// exactly one (b,n) row -> BN stats via one 5-step butterfly + 1 atomic pair/row.
__global__ __launch_bounds__(1024) void ln_apply_split_k(const float4* __restrict__ x,
                                                         const float4* __restrict__ w,
                                                         const float4* __restrict__ bia,
                                                         const float2* __restrict__ part,
                                                         uint2* __restrict__ xhi,
                                                         uint2* __restrict__ xlo,
                                                         float* __restrict__ bnacc) {
    __shared__ float2 musd;
    int tid = threadIdx.x;
    int b = blockIdx.x >> 3;            // 8 blocks per batch (16384 floats each)
    if (tid < 32) {
        float2 p = part[b * 32 + tid];
        float s = p.x, s2 = p.y;
#pragma unroll
        for (int o = 16; o > 0; o >>= 1) { s += __shfl_xor(s, o, 32); s2 += __shfl_xor(s2, o, 32); }
        if (tid == 0) {
            float inv = 1.f / (Nn * Td);
            float mu = s * inv;
            float var = s2 * inv - mu * mu;
            musd = make_float2(mu, rsqrtf(var + EPSN));
        }
    }
    __syncthreads();
    float mu = musd.x, rs = musd.y;
    int i40 = blockIdx.x * 4096 + tid * 4;   // float4 index, 4 consecutive per thread
    float so = 0.f, so2 = 0.f;
#pragma unroll
    for (int j = 0; j < 4; ++j) {
        int i = i40 + j;
        int r = i & ((Nn * Td / 4) - 1);
        float4 xv = x[i], wv = w[r], bv = bia[r];
        float4 o;
        o.x = (xv.x - mu) * rs * wv.x + bv.x;
        o.y = (xv.y - mu) * rs * wv.y + bv.y;
        o.z = (xv.z - mu) * rs * wv.z + bv.z;
        o.w = (xv.w - mu) * rs * wv.w + bv.w;
        so += o.x + o.y + o.z + o.w;
        so2 += o.x * o.x + o.y * o.y + o.z * o.z + o.w * o.w;
        u16 hx = f2b(o.x), hy = f2b(o.y), hz = f2b(o.z), hw = f2b(o.w);
        uint2 ph, pl;
        ph.x = (unsigned)hx | ((unsigned)hy << 16);
        ph.y = (unsigned)hz | ((unsigned)hw << 16);
        pl.x = (unsigned)f2b(o.x - b2f(hx)) | ((unsigned)f2b(o.y - b2f(hy)) << 16);
        pl.y = (unsigned)f2b(o.z - b2f(hz)) | ((unsigned)f2b(o.w - b2f(hw)) << 16);
        xhi[i] = ph;
        xlo[i] = pl;
    }
    // 32-lane half-wave = one full (b,n) row of 512 floats
#pragma unroll
    for (int o = 16; o > 0; o >>= 1) { so += __shfl_xor(so, o); so2 += __shfl_xor(so2, o); }
    if ((tid & 31) == 0) {
        int n = (i40 >> 7) & 255;        // row = float4_idx / 128
        atomicAdd(&bnacc[2 * n], so);
        atomicAdd(&bnacc[2 * n + 1], so2);
    }
}

// ---------------- top-k: wave-per-row radix select, zero __syncthreads ----------------
__global__ __launch_bounds__(256) void topk_sel_k(const float4* __restrict__ sc4,
                                                  const float4* __restrict__ dis4,
                                                  uint2* __restrict__ bA2,
                                                  float* __restrict__ dinv) {
    __shared__ int hist[4][256];
    __shared__ int2 pr[4];
    int tid = threadIdx.x, lane = tid & 63, wv = tid >> 6;
    int row = blockIdx.x * 4 + wv;
    int n = row & 255;
    float4 v = sc4[(size_t)row * 64 + lane];
    float vv[4] = { v.x, v.y, v.z, v.w };
    unsigned key[4];
#pragma unroll
    for (int j = 0; j < 4; ++j) {
        unsigned fu = __float_as_uint(vv[j]);
        key[j] = (fu & 0x80000000u) ? ~fu : (fu | 0x80000000u);
    }
    unsigned pref = 0u;
    int rank = Nn - NMAXS;   // 205
#pragma unroll
    for (int shift = 24; shift >= 0; shift -= 8) {
        unsigned mhi = (shift == 24) ? 0u : (0xFFFFFFFFu << (shift + 8));
        *(int4*)&hist[wv][lane * 4] = make_int4(0, 0, 0, 0);
        __threadfence_block();
#pragma unroll
        for (int j = 0; j < 4; ++j)
            if ((key[j] & mhi) == pref) atomicAdd(&hist[wv][(key[j] >> shift) & 255], 1);
        __threadfence_block();
        int4 h = *(const int4*)&hist[wv][lane * 4];
        int s0 = h.x, s1 = s0 + h.y, s2 = s1 + h.z, s3 = s2 + h.w;
        int t = s3;
#pragma unroll
        for (int o = 1; o < 64; o <<= 1) { int y = __shfl_up(t, o, 64); if (lane >= o) t += y; }
        int excl = t - s3;
        int below[4] = { excl, excl + s0, excl + s1, excl + s2 };
        int cum[4]   = { excl + s0, excl + s1, excl + s2, excl + s3 };
#pragma unroll
        for (int j = 0; j < 4; ++j) {
            if (cum[j] > rank && below[j] <= rank)
                pr[wv] = make_int2((int)(pref | ((unsigned)(lane * 4 + j) << shift)), rank - below[j]);
        }
        __threadfence_block();
        int2 p = pr[wv];
        pref = (unsigned)p.x;
        rank = p.y;
    }
    float kth = __uint_as_float((pref & 0x80000000u) ? (pref & 0x7FFFFFFFu) : ~pref);
    float4 dv = dis4[(size_t)n * 64 + lane];
    float dd[4] = { dv.x, dv.y, dv.z, dv.w };
    float s = 0.f;
    u16 o16[4];
#pragma unroll
    for (int j = 0; j < 4; ++j) {
        float as = (vv[j] >= kth) ? vv[j] : 0.f;
        float a = fmaxf(as + dd[j], 0.f);
        o16[j] = f2b(a);
        s += a;
    }
    uint2 ow;
    ow.x = (unsigned)o16[0] | ((unsigned)o16[1] << 16);
    ow.y = (unsigned)o16[2] | ((unsigned)o16[3] << 16);
    bA2[(size_t)row * 64 + lane] = ow;
#pragma unroll
    for (int o = 32; o > 0; o >>= 1) s += __shfl_down(s, o, 64);
    if (lane == 0) dinv[row] = rsqrtf(s + EPSD);
}

// ---------------- fused BN-apply + full Chebyshev recursion (Tx0, Tx1, Tx2) ----------------
// Block = (t-slice of 128 cols, batch). 512 threads / 8 waves (4 row-groups x 2 col-groups).
// Zt[128 t][256 m] bf16 stays LDS-resident; A streamed twice with double-buffered DMA.
__global__ __launch_bounds__(512) void cheb_fused_k(const uint2* __restrict__ xhi,
                                                    const uint2* __restrict__ xlo,
                                                    const float* __restrict__ bnacc,
                                                    const float* __restrict__ g,
                                                    const float* __restrict__ be,
                                                    const float* __restrict__ dinv,
                                                    const u16* __restrict__ bA,
                                                    u16* __restrict__ cat) {
    __shared__ u16 Zt[128 * 256];          // 64KB  [t][m-chunk swizzled]
    __shared__ u16 As[2][2][256 * 32];     // 64KB  [buf][half][row*32 + chunk]
    __shared__ float scl[256], sft[256], dvv[256];
    int z = blockIdx.y, tb = blockIdx.x;   // tb in [0,4): 128-col t-slice
    int tid = threadIdx.x, lane = tid & 63, wave = tid >> 6;
    const u16* Ab = bA + (size_t)z * (Nn * Nn);
    int wr = (wave >> 1) * 64, wc = (wave & 1) * 64;
    int fr = lane & 15, fq = lane >> 4;

    // phase 0: per-node BN scale/shift + dinv into LDS
    if (tid < 256) {
        const float inv = 1.f / (Bb * Td);
        float s = bnacc[2 * tid], s2 = bnacc[2 * tid + 1];
        float mu = s * inv;
        float var = s2 * inv - mu * mu;
        float rs = rsqrtf(var + EPSN);
        float sc_ = rs * g[tid];
        scl[tid] = sc_;
        sft[tid] = be[tid] - mu * sc_;
        dvv[tid] = dinv[z * 256 + tid];
    }
    __syncthreads();

    auto stageA = [&](int buf, int k0) {
#pragma unroll
        for (int h = 0; h < 2; ++h) {
#pragma unroll
            for (int sub = 0; sub < 2; ++sub) {
                int r = wave * 32 + sub * 16 + (lane >> 2);
                int kc = ((lane & 3) ^ swz4(r)) << 3;
                gload_lds(Ab + (size_t)r * 256 + k0 + h * 32 + kc,
                          &As[buf][h][(wave * 32 + sub * 16) * 32]);
            }
        }
    };

    f32x4 acc[4][4] = {};
    auto compute = [&](int buf, int kk) {
#pragma unroll
        for (int h = 0; h < 2; ++h) {
            short8 af[4], bf[4];
#pragma unroll
            for (int mi = 0; mi < 4; ++mi) {
                int rr = wr + mi * 16 + fr;
                af[mi] = *(const short8*)&As[buf][h][rr * 32 + ((fq ^ swz4(rr)) << 3)];
            }
            int c5 = ((kk + h * 32) >> 3) + fq;
#pragma unroll
            for (int ni = 0; ni < 4; ++ni) {
                int cc = wc + ni * 16 + fr;
                bf[ni] = *(const short8*)&Zt[cc * 256 + ((c5 ^ (cc & 31)) << 3)];
            }
#pragma unroll
            for (int mi = 0; mi < 4; ++mi)
#pragma unroll
                for (int ni = 0; ni < 4; ++ni)
                    acc[mi][ni] = __builtin_amdgcn_mfma_f32_16x16x32_bf16(af[mi], bf[ni], acc[mi][ni], 0, 0, 0);
        }
    };

    // issue GEMM1 step-0 DMA; it lands during Z-build
    stageA(0, 0);

    // Z-build: BN apply -> write cat Tx0 (global) + Z0 = dv*Tx0 (LDS, transposed)
    {
        int mrow = tid >> 5;            // 16 rows per pass
        int c = tid & 31;               // uint2 col within 32 (4 t each)
        int t4g0 = tb * 32;
#pragma unroll 4
        for (int p = 0; p < 16; ++p) {
            int m = p * 16 + mrow;
            size_t idx = ((size_t)(z * 256 + m)) * 128 + t4g0 + c;
            float4 v = unp2(xhi[idx], xlo[idx]);
            float sc_ = scl[m], sh_ = sft[m], dv = dvv[m];
            v.x = v.x * sc_ + sh_; v.y = v.y * sc_ + sh_;
            v.z = v.z * sc_ + sh_; v.w = v.w * sc_ + sh_;
            uint2 o2;
            o2.x = (unsigned)f2b(v.x) | ((unsigned)f2b(v.y) << 16);
            o2.y = (unsigned)f2b(v.z) | ((unsigned)f2b(v.w) << 16);
            *(uint2*)&cat[((size_t)(z * 256 + m)) * 1536 + (size_t)(t4g0 + c) * 4] = o2;
            u16 zv[4] = { f2b(v.x * dv), f2b(v.y * dv), f2b(v.z * dv), f2b(v.w * dv) };
#pragma unroll
            for (int j = 0; j < 4; ++j) {
                int tl = c * 4 + j;     // local t in [0,128)
                Zt[tl * 256 + (((m >> 3) ^ (tl & 31)) << 3) + (m & 7)] = zv[j];
            }
        }
    }
    __syncthreads();   // Z0 visible + GEMM1 step-0 DMA drained

    // GEMM1: Y1 = A @ Z0   (K=256, 4 steps of 64)
    for (int s = 0; s < 4; ++s) {
        if (s < 3) stageA((s + 1) & 1, (s + 1) * 64);
        compute(s & 1, s * 64);
        __syncthreads();
    }

    // prefetch GEMM2 step-0 (overlaps epilogue-1)
    stageA(0, 0);

    // epilogue 1: Tx1 = dv[n]*Y1 -> cat[.,512:1024]; Z1 = dv[n]*Tx1 -> Zt
#pragma unroll
    for (int mi = 0; mi < 4; ++mi) {
#pragma unroll
        for (int rg = 0; rg < 4; ++rg) {
            int n = wr + mi * 16 + fq * 4 + rg;
            float dv = dvv[n];
            size_t rowb = (size_t)(z * 256 + n) * 1536;
#pragma unroll
            for (int ni = 0; ni < 4; ++ni) {
                int tl = wc + ni * 16 + fr;
                float tx1 = dv * acc[mi][ni][rg];
                cat[rowb + 512 + tb * 128 + tl] = f2b(tx1);
                Zt[tl * 256 + (((n >> 3) ^ (tl & 31)) << 3) + (n & 7)] = f2b(dv * tx1);
            }
            acc[mi][0][rg] = 0.f; acc[mi][1][rg] = 0.f;
            acc[mi][2][rg] = 0.f; acc[mi][3][rg] = 0.f;
        }
    }
    __syncthreads();   // Z1 visible + GEMM2 step-0 DMA drained

    // GEMM2: Y2 = A @ Z1
    for (int s = 0; s < 4; ++s) {
        if (s < 3) stageA((s + 1) & 1, (s + 1) * 64);
        compute(s & 1, s * 64);
        if (s < 3) __syncthreads();
    }

    // epilogue 2: Tx2 = 2*dv[n]*Y2 - Tx0 -> cat[.,1024:1536]  (Tx0 read back, L2-hot)
    __threadfence_block();
#pragma unroll
    for (int mi = 0; mi < 4; ++mi) {
#pragma unroll
        for (int rg = 0; rg < 4; ++rg) {
            int n = wr + mi * 16 + fq * 4 + rg;
            float dv2 = 2.f * dvv[n];
            size_t rowb = (size_t)(z * 256 + n) * 1536;
#pragma unroll
            for (int ni = 0; ni < 4; ++ni) {
                int tg = tb * 128 + wc + ni * 16 + fr;
                float v = dv2 * acc[mi][ni][rg] - b2f(cat[rowb + tg]);
                cat[rowb + 1024 + tg] = f2b(v);
            }
        }
    }
}

// ---------------- bf16 MFMA GEMM, NT, DMA + double-buffered prefetch, BK=64 ----------------
// R2-measured-best config for the final K=1536 gemm (40.4 us). Do not re-tile.
template <bool FINAL, bool WF32>
__global__ __launch_bounds__(256) void gemm_bf_k(const u16* __restrict__ A,
                                                 const u16* __restrict__ Bt,
                                                 const float* __restrict__ bias,
                                                 float* __restrict__ C,
                                                 int Ncols, int K) {
    __shared__ u16 As[2][8192];   // [buf][h*4096 + row*32 + swizzled chunk]
    __shared__ u16 Bs[2][8192];
    const u16* Ag = A;
    const u16* Bg = Bt;
    int br = blockIdx.x * 128, bc = blockIdx.y * 128;
    int tid = threadIdx.x, lane = tid & 63, wave = tid >> 6;
    int wr = (wave >> 1) * 64, wc = (wave & 1) * 64;
    int i0 = wave * 2;
    int rl0 = i0 * 16 + (lane >> 2);
    int rl1 = rl0 + 16;
    int cp = lane & 3;
    int ca0 = (cp ^ swz4(rl0)) * 8;
    int ca1 = (cp ^ swz4(rl1)) * 8;
    const u16* gA0 = Ag + (size_t)(br + rl0) * K + ca0;
    const u16* gA1 = Ag + (size_t)(br + rl1) * K + ca1;
    const u16* gB0 = Bg + (size_t)(bc + rl0) * K + ca0;
    const u16* gB1 = Bg + (size_t)(bc + rl1) * K + ca1;
    f32x4 acc[4][4] = {};
    int fr = lane & 15, fq = lane >> 4;
    auto stage = [&](int buf, int k0) {
#pragma unroll
        for (int h = 0; h < 2; ++h) {
            int kk = k0 + h * 32;
            int ho = h * 4096;
            gload_lds(gA0 + kk, &As[buf][ho + i0 * 512]);
            gload_lds(gA1 + kk, &As[buf][ho + i0 * 512 + 512]);
            gload_lds(gB0 + kk, &Bs[buf][ho + i0 * 512]);
            gload_lds(gB1 + kk, &Bs[buf][ho + i0 * 512 + 512]);
        }
    };
    int nIter = K >> 6;
    stage(0, 0);
    for (int it = 0; it < nIter; ++it) {
        int cur = it & 1;
        __syncthreads();                       // drains stage(cur) issued one iter ago
        if (it + 1 < nIter) stage(1 - cur, (it + 1) << 6);
#pragma unroll
        for (int h = 0; h < 2; ++h) {
            int ho = h * 4096;
            short8 af[4], bf[4];
#pragma unroll
            for (int mi = 0; mi < 4; ++mi) {
                int rr = wr + mi * 16 + fr;
                af[mi] = *(const short8*)&As[cur][ho + rr * 32 + ((fq ^ swz4(rr)) << 3)];
            }
#pragma unroll
            for (int ni = 0; ni < 4; ++ni) {
                int rr = wc + ni * 16 + fr;
                bf[ni] = *(const short8*)&Bs[cur][ho + rr * 32 + ((fq ^ swz4(rr)) << 3)];
            }
#pragma unroll
            for (int mi = 0; mi < 4; ++mi)
#pragma unroll
                for (int ni = 0; ni < 4; ++ni)
                    acc[mi][ni] = __builtin_amdgcn_mfma_f32_16x16x32_bf16(af[mi], bf[ni], acc[mi][ni], 0, 0, 0);
        }
    }
#pragma unroll
    for (int mi = 0; mi < 4; ++mi) {
#pragma unroll
        for (int rg = 0; rg < 4; ++rg) {
            int row = br + wr + mi * 16 + fq * 4 + rg;
#pragma unroll
            for (int ni = 0; ni < 4; ++ni) {
                int col = bc + wc + ni * 16 + fr;
                float v = acc[mi][ni][rg];
                if (FINAL) v = fmaxf(v + bias[col], 0.f);
                if (WF32) C[(size_t)row * Ncols + col] = v;
            }
        }
    }
}

// ---------------- split-bf16 3-MFMA GEMM, NT, DMA + double-buffered prefetch, BK=32 ----------------
// NB = B-tile width (128 or 64). NB=64 doubles grid for small-N shapes (occupancy).
template <bool BIAS, bool WSPLIT, bool WF32, int NB>
__global__ __launch_bounds__(256) void gemm_bf3_k(const u16* __restrict__ Ahi,
                                                  const u16* __restrict__ Alo,
                                                  const u16* __restrict__ Bhi,
                                                  const u16* __restrict__ Blo,
                                                  const float* __restrict__ bias,
                                                  float* __restrict__ C,
                                                  u16* __restrict__ Chi,
                                                  u16* __restrict__ Clo,
                                                  int Ncols, int K,
                                                  long long sA, long long sB, long long sC) {
    constexpr int NNI = NB / 32;           // B-fragments per wave
    __shared__ u16 Ash[2][4096];
    __shared__ u16 Asl[2][4096];
    __shared__ u16 Bsh[2][NB * 32];
    __shared__ u16 Bsl[2][NB * 32];
    int z = blockIdx.z;
    const u16* Agh = Ahi + (size_t)z * sA;
    const u16* Agl = Alo + (size_t)z * sA;
    const u16* Bgh = Bhi + (size_t)z * sB;
    const u16* Bgl = Blo + (size_t)z * sB;
    int br = blockIdx.x * 128, bc = blockIdx.y * NB;
    int tid = threadIdx.x, lane = tid & 63, wave = tid >> 6;
    int wr = (wave >> 1) * 64, wc = (wave & 1) * (NB / 2);
    int i0 = wave * 2;
    int rl0 = i0 * 16 + (lane >> 2);
    int rl1 = rl0 + 16;
    int cp = lane & 3;
    int ca0 = (cp ^ swz4(rl0)) * 8;
    int ca1 = (cp ^ swz4(rl1)) * 8;
    size_t oA0 = (size_t)(br + rl0) * K + ca0;
    size_t oA1 = (size_t)(br + rl1) * K + ca1;
    int rB0 = (NB == 128) ? rl0 : (wave * 16 + (lane >> 2));
    int cB0 = (cp ^ swz4(rB0)) * 8;
    size_t oB0 = (size_t)(bc + rB0) * K + cB0;
    size_t oB1 = (size_t)(bc + rl1) * K + ca1;   // used only when NB==128
    f32x4 acc[4][NNI] = {};
    int fr = lane & 15, fq = lane >> 4;
    auto stage = [&](int buf, int kk) {
        gload_lds(Agh + oA0 + kk, &Ash[buf][i0 * 512]);
        gload_lds(Agh + oA1 + kk, &Ash[buf][i0 * 512 + 512]);
        gload_lds(Agl + oA0 + kk, &Asl[buf][i0 * 512]);
        gload_lds(Agl + oA1 + kk, &Asl[buf][i0 * 512 + 512]);
        if constexpr (NB == 128) {
            gload_lds(Bgh + oB0 + kk, &Bsh[buf][i0 * 512]);
            gload_lds(Bgh + oB1 + kk, &Bsh[buf][i0 * 512 + 512]);
            gload_lds(Bgl + oB0 + kk, &Bsl[buf][i0 * 512]);
            gload_lds(Bgl + oB1 + kk, &Bsl[buf][i0 * 512 + 512]);
        } else {
            gload_lds(Bgh + oB0 + kk, &Bsh[buf][wave * 512]);
            gload_lds(Bgl + oB0 + kk, &Bsl[buf][wave * 512]);
        }
    };
    int nIter = K >> 5;
    stage(0, 0);
    for (int it = 0; it < nIter; ++it) {
        int cur = it & 1;
        __syncthreads();
        if (it + 1 < nIter) stage(1 - cur, (it + 1) << 5);
        short8 afh[4], afl[4], bfh[NNI], bfl[NNI];
#pragma unroll
        for (int mi = 0; mi < 4; ++mi) {
            int rr = wr + mi * 16 + fr;
            int off = rr * 32 + ((fq ^ swz4(rr)) << 3);
            afh[mi] = *(const short8*)&Ash[cur][off];
            afl[mi] = *(const short8*)&Asl[cur][off];
        }
#pragma unroll
        for (int ni = 0; ni < NNI; ++ni) {
            int rr = wc + ni * 16 + fr;
            int off = rr * 32 + ((fq ^ swz4(rr)) << 3);
            bfh[ni] = *(const short8*)&Bsh[cur][off];
            bfl[ni] = *(const short8*)&Bsl[cur][off];
        }
#pragma unroll
        for (int mi = 0; mi < 4; ++mi)
#pragma unroll
            for (int ni = 0; ni < NNI; ++ni) {
                acc[mi][ni] = __builtin_amdgcn_mfma_f32_16x16x32_bf16(afh[mi], bfh[ni], acc[mi][ni], 0, 0, 0);
                acc[mi][ni] = __builtin_amdgcn_mfma_f32_16x16x32_bf16(afh[mi], bfl[ni], acc[mi][ni], 0, 0, 0);
                acc[mi][ni] = __builtin_amdgcn_mfma_f32_16x16x32_bf16(afl[mi], bfh[ni], acc[mi][ni], 0, 0, 0);
            }
    }
    float* Cp = WF32 ? C + (size_t)z * sC : nullptr;
    u16* Chp = WSPLIT ? Chi + (size_t)z * sC : nullptr;
    u16* Clp = WSPLIT ? Clo + (size_t)z * sC : nullptr;
#pragma unroll
    for (int mi = 0; mi < 4; ++mi) {
#pragma unroll
        for (int rg = 0; rg < 4; ++rg) {
            int row = br + wr + mi * 16 + fq * 4 + rg;
            size_t rb = (size_t)row * Ncols;
#pragma unroll
            for (int ni = 0; ni < NNI; ++ni) {
                int col = bc + wc + ni * 16 + fr;
                float v = acc[mi][ni][rg];
                if (BIAS) v += bias[col];
                if (WF32) Cp[rb + col] = v;
                if (WSPLIT) {
                    u16 h = f2b(v);
                    Chp[rb + col] = h;
                    Clp[rb + col] = f2b(v - b2f(h));
                }
            }
        }
    }
}

extern "C" void kernel_launch(void* const* d_in, const int* in_sizes, int n_in,
                              void* d_out, int out_size, void* d_ws, size_t ws_size,
                              hipStream_t stream) {
    const float* x      = (const float*)d_in[0];
    const float* dis    = (const float*)d_in[1];
    const float* ln_w   = (const float*)d_in[2];
    const float* ln_b   = (const float*)d_in[3];
    const float* bn_g   = (const float*)d_in[4];
    const float* bn_b   = (const float*)d_in[5];
    const float* li_w   = (const float*)d_in[6];
    const float* li_b   = (const float*)d_in[7];
    const float* cheb_w = (const float*)d_in[8];
    const float* cheb_b = (const float*)d_in[9];
    float* out = (float*)d_out;

    const size_t BNT = (size_t)Bb * Nn * Td;   // 8388608
    const size_t BNN = (size_t)Bb * Nn * Nn;   // 4194304
    float* ws = (float*)d_ws;
    u16* xhi = (u16*)ws;
    u16* xlo = xhi + BNT;
    u16* xphi = (u16*)(ws + BNT);
    u16* xplo = xphi + BNT;
    u16* cat  = (u16*)(ws + BNT);               // [16384][1536] bf16 (reuses xp region after scores)
    float* sc = ws + 2 * BNT;
    float* p4 = ws + 2 * BNT + BNN;
    float* p5 = p4 + BNT / 2;
    u16* bA = (u16*)p5;                          // BNN u16
    float* p6 = p5 + BNN / 2;
    u16* bWc = (u16*)p6;                         // 512*1536 u16
    float* p7 = p6 + (512 * 1536) / 2;
    u16* liwhi = (u16*)p7;                       // 512*512 u16 x2
    u16* liwlo = liwhi + 512 * 512;
    float* p8 = p7 + 262144;
    float* dinv = p8;                            // 16384
    float2* part = (float2*)(dinv + 16384);      // 2048 float2
    float* bnacc = (float*)(part + 2048);        // 512 floats (BN sum/sumsq accum)

    // 1. LN stage A + param prep + bnacc zero (one launch, grid-z split)
    hipLaunchKernelGGL(prep_ln_partial_k, dim3(32, Bb, 2), dim3(256), 0, stream,
                       (const float4*)x, part, cheb_w, bWc, li_w, liwhi, liwlo, bnacc);
    // 2. LN apply (block-wide finalize broadcast) -> hi/lo split; BN stats via atomics
    hipLaunchKernelGGL(ln_apply_split_k, dim3(BNT / 16384), dim3(1024), 0, stream,
                       (const float4*)x, (const float4*)ln_w, (const float4*)ln_b, part,
                       (uint2*)xhi, (uint2*)xlo, bnacc);
    // 3. xp = x_ln @ li_w^T + li_b  (split-bf16 3-MFMA -> hi/lo)
    hipLaunchKernelGGL((gemm_bf3_k<true, true, false, 128>), dim3(Bb * Nn / 128, Td / 128, 1), dim3(256), 0, stream,
                       xhi, xlo, liwhi, liwlo, li_b, (float*)nullptr, xphi, xplo,
                       Td, Td, 0LL, 0LL, 0LL);
    // 4. scores[b] = xp[b] @ xp[b]^T  (split-bf16 -> fp32; NB=64 -> 512 blocks = 2/CU)
    hipLaunchKernelGGL((gemm_bf3_k<false, false, true, 64>), dim3(Nn / 128, Nn / 64, Bb), dim3(256), 0, stream,
                       xphi, xplo, xphi, xplo, (const float*)nullptr, sc, (u16*)nullptr, (u16*)nullptr,
                       Nn, Td, (long long)Nn * Td, (long long)Nn * Td, (long long)Nn * Nn);
    // 5. top-k wave-per-row radix select; A = relu(A_s + dis) -> bf16 bA; dinv
    hipLaunchKernelGGL(topk_sel_k, dim3(Bb * Nn / 4), dim3(256), 0, stream,
                       (const float4*)sc, (const float4*)dis, (uint2*)bA, dinv);
    // 6. fused BN-apply + Chebyshev (512 thr / 8 waves): writes cat Tx0|Tx1|Tx2
    hipLaunchKernelGGL(cheb_fused_k, dim3(Td / 128, Bb), dim3(512), 0, stream,
                       (const uint2*)xhi, (const uint2*)xlo, bnacc, bn_g, bn_b,
                       dinv, bA, cat);
    // 7. out = relu([Tx0|Tx1|Tx2] @ [W0;W1;W2]^T + cheb_b)  (K=1536, R2-best 128^2 BK=64)
    hipLaunchKernelGGL((gemm_bf_k<true, true>), dim3(Bb * Nn / 128, Td / 128, 1), dim3(256), 0, stream,
                       cat, bWc, cheb_b, out, Td, 1536);
}

// Round 11
// 260.206 us; speedup vs baseline: 1.0359x; 1.0230x over previous
//
#include <hip/hip_runtime.h>
#include <cstddef>

static constexpr int Bb = 64;     // batch
static constexpr int Nn = 256;    // nodes
static constexpr int Td = 512;    // time dim
static constexpr int NMAXS = 51;  // 256 // 5
static constexpr float EPSN = 1e-5f;
static constexpr float EPSD = 1e-10f;

typedef unsigned short u16;
typedef __attribute__((ext_vector_type(8))) short short8;
typedef __attribute__((ext_vector_type(4))) float f32x4;

__device__ __forceinline__ u16 f2b(float f) {
    unsigned u = __float_as_uint(f);
    return (u16)((u + 0x7fffu + ((u >> 16) & 1u)) >> 16);
}
__device__ __forceinline__ float b2f(u16 h) {
    return __uint_as_float(((unsigned)h) << 16);
}
__device__ __forceinline__ float4 unp2(uint2 h, uint2 l) {
    float4 r;
    r.x = b2f((u16)h.x) + b2f((u16)l.x);
    r.y = b2f((u16)(h.x >> 16)) + b2f((u16)(l.x >> 16));
    r.z = b2f((u16)h.y) + b2f((u16)l.y);
    r.w = b2f((u16)(h.y >> 16)) + b2f((u16)(l.y >> 16));
    return r;
}

// async global->LDS DMA, 16B/lane. LDS dest = wave-uniform base + lane*16.
__device__ __forceinline__ void gload_lds(const u16* g, u16* l) {
    __builtin_amdgcn_global_load_lds(
        (const __attribute__((address_space(1))) unsigned int*)g,
        (__attribute__((address_space(3))) unsigned int*)l, 16, 0, 0);
}
__device__ __forceinline__ int swz4(int r) { return (r ^ (r >> 2)) & 3; }

// ---------------- LN stats stage A (z=0) + param prep (z=1) + bnacc zero ----------------
__global__ __launch_bounds__(256) void prep_ln_partial_k(const float4* __restrict__ x,
                                                         float2* __restrict__ part,
                                                         const float* __restrict__ cheb_w,
                                                         u16* __restrict__ bWc,
                                                         const float* __restrict__ li_w,
                                                         u16* __restrict__ liwhi,
                                                         u16* __restrict__ liwlo,
                                                         float* __restrict__ bnacc) {
    __shared__ float sh[256], sh2[256];
    __shared__ u16 tile[32][33];
    if (blockIdx.z == 0) {
        int b = blockIdx.y, c = blockIdx.x;
        int base = b * 32768 + c * 1024;
        float s = 0.f, s2 = 0.f;
#pragma unroll
        for (int j = 0; j < 4; ++j) {
            float4 v = x[base + j * 256 + threadIdx.x];
            s += v.x + v.y + v.z + v.w;
            s2 += v.x * v.x + v.y * v.y + v.z * v.z + v.w * v.w;
        }
        sh[threadIdx.x] = s; sh2[threadIdx.x] = s2;
        __syncthreads();
        for (int o = 128; o > 0; o >>= 1) {
            if (threadIdx.x < o) { sh[threadIdx.x] += sh[threadIdx.x + o]; sh2[threadIdx.x] += sh2[threadIdx.x + o]; }
            __syncthreads();
        }
        if (threadIdx.x == 0) part[b * 32 + c] = make_float2(sh[0], sh2[0]);
    } else {
        int lin = blockIdx.y * 32 + blockIdx.x;
        if (lin == 1024) {
            // zero BN accumulator (consumed by ln_apply's atomics next kernel)
            bnacc[threadIdx.x] = 0.f;
            bnacc[threadIdx.x + 256] = 0.f;
            return;
        }
        if (lin > 1024) return;
        int bx = lin & 15, by = (lin >> 4) & 15, bz = lin >> 8;
        int c0 = bx * 32, r0 = by * 32;
        int tx = threadIdx.x & 31, ty = threadIdx.x >> 5;
        if (bz < 3) {
            const float* ip = cheb_w + (size_t)bz * Td * Td;
#pragma unroll
            for (int i = 0; i < 4; ++i) {
                int r = ty + i * 8;
                tile[r][tx] = f2b(ip[(size_t)(r0 + r) * Td + c0 + tx]);
            }
            __syncthreads();
#pragma unroll
            for (int i = 0; i < 4; ++i) {
                int c = ty + i * 8;
                bWc[(size_t)(c0 + c) * 1536 + bz * 512 + (r0 + tx)] = tile[tx][c];
            }
        } else {
#pragma unroll
            for (int i = 0; i < 4; ++i) {
                int r = r0 + ty + i * 8;
                size_t idx = (size_t)r * Td + c0 + tx;
                float v = li_w[idx];
                u16 h = f2b(v);
                liwhi[idx] = h;
                liwlo[idx] = f2b(v - b2f(h));
            }
        }
    }
}

// LN apply: 1024-thread blocks, 4 x float4 per thread. LN-finalize runs ONCE per
// block (lanes 0-31 butterfly -> LDS broadcast). Each 32-lane half-wave covers
// exactly one (b,n) row -> BN stats via one 5-step butterfly + 1 atomic pair/row.
__global__ __launch_bounds__(1024) void ln_apply_split_k(const float4* __restrict__ x,
                                                         const float4* __restrict__ w,
                                                         const float4* __restrict__ bia,
                                                         const float2* __restrict__ part,
                                                         uint2* __restrict__ xhi,
                                                         uint2* __restrict__ xlo,
                                                         float* __restrict__ bnacc) {
    __shared__ float2 musd;
    int tid = threadIdx.x;
    int b = blockIdx.x >> 3;            // 8 blocks per batch (16384 floats each)
    if (tid < 32) {
        float2 p = part[b * 32 + tid];
        float s = p.x, s2 = p.y;
#pragma unroll
        for (int o = 16; o > 0; o >>= 1) { s += __shfl_xor(s, o, 32); s2 += __shfl_xor(s2, o, 32); }
        if (tid == 0) {
            float inv = 1.f / (Nn * Td);
            float mu = s * inv;
            float var = s2 * inv - mu * mu;
            musd = make_float2(mu, rsqrtf(var + EPSN));
        }
    }
    __syncthreads();
    float mu = musd.x, rs = musd.y;
    int i40 = blockIdx.x * 4096 + tid * 4;   // float4 index, 4 consecutive per thread
    float so = 0.f, so2 = 0.f;
#pragma unroll
    for (int j = 0; j < 4; ++j) {
        int i = i40 + j;
        int r = i & ((Nn * Td / 4) - 1);
        float4 xv = x[i], wv = w[r], bv = bia[r];
        float4 o;
        o.x = (xv.x - mu) * rs * wv.x + bv.x;
        o.y = (xv.y - mu) * rs * wv.y + bv.y;
        o.z = (xv.z - mu) * rs * wv.z + bv.z;
        o.w = (xv.w - mu) * rs * wv.w + bv.w;
        so += o.x + o.y + o.z + o.w;
        so2 += o.x * o.x + o.y * o.y + o.z * o.z + o.w * o.w;
        u16 hx = f2b(o.x), hy = f2b(o.y), hz = f2b(o.z), hw = f2b(o.w);
        uint2 ph, pl;
        ph.x = (unsigned)hx | ((unsigned)hy << 16);
        ph.y = (unsigned)hz | ((unsigned)hw << 16);
        pl.x = (unsigned)f2b(o.x - b2f(hx)) | ((unsigned)f2b(o.y - b2f(hy)) << 16);
        pl.y = (unsigned)f2b(o.z - b2f(hz)) | ((unsigned)f2b(o.w - b2f(hw)) << 16);
        xhi[i] = ph;
        xlo[i] = pl;
    }
    // 32-lane half-wave = one full (b,n) row of 512 floats
#pragma unroll
    for (int o = 16; o > 0; o >>= 1) { so += __shfl_xor(so, o); so2 += __shfl_xor(so2, o); }
    if ((tid & 31) == 0) {
        int n = (i40 >> 7) & 255;        // row = float4_idx / 128
        atomicAdd(&bnacc[2 * n], so);
        atomicAdd(&bnacc[2 * n + 1], so2);
    }
}

// ---------------- top-k: wave-per-row radix select, zero __syncthreads ----------------
__global__ __launch_bounds__(256) void topk_sel_k(const float4* __restrict__ sc4,
                                                  const float4* __restrict__ dis4,
                                                  uint2* __restrict__ bA2,
                                                  float* __restrict__ dinv) {
    __shared__ int hist[4][256];
    __shared__ int2 pr[4];
    int tid = threadIdx.x, lane = tid & 63, wv = tid >> 6;
    int row = blockIdx.x * 4 + wv;
    int n = row & 255;
    float4 v = sc4[(size_t)row * 64 + lane];
    float vv[4] = { v.x, v.y, v.z, v.w };
    unsigned key[4];
#pragma unroll
    for (int j = 0; j < 4; ++j) {
        unsigned fu = __float_as_uint(vv[j]);
        key[j] = (fu & 0x80000000u) ? ~fu : (fu | 0x80000000u);
    }
    unsigned pref = 0u;
    int rank = Nn - NMAXS;   // 205
#pragma unroll
    for (int shift = 24; shift >= 0; shift -= 8) {
        unsigned mhi = (shift == 24) ? 0u : (0xFFFFFFFFu << (shift + 8));
        *(int4*)&hist[wv][lane * 4] = make_int4(0, 0, 0, 0);
        __threadfence_block();
#pragma unroll
        for (int j = 0; j < 4; ++j)
            if ((key[j] & mhi) == pref) atomicAdd(&hist[wv][(key[j] >> shift) & 255], 1);
        __threadfence_block();
        int4 h = *(const int4*)&hist[wv][lane * 4];
        int s0 = h.x, s1 = s0 + h.y, s2 = s1 + h.z, s3 = s2 + h.w;
        int t = s3;
#pragma unroll
        for (int o = 1; o < 64; o <<= 1) { int y = __shfl_up(t, o, 64); if (lane >= o) t += y; }
        int excl = t - s3;
        int below[4] = { excl, excl + s0, excl + s1, excl + s2 };
        int cum[4]   = { excl + s0, excl + s1, excl + s2, excl + s3 };
#pragma unroll
        for (int j = 0; j < 4; ++j) {
            if (cum[j] > rank && below[j] <= rank)
                pr[wv] = make_int2((int)(pref | ((unsigned)(lane * 4 + j) << shift)), rank - below[j]);
        }
        __threadfence_block();
        int2 p = pr[wv];
        pref = (unsigned)p.x;
        rank = p.y;
    }
    float kth = __uint_as_float((pref & 0x80000000u) ? (pref & 0x7FFFFFFFu) : ~pref);
    float4 dv = dis4[(size_t)n * 64 + lane];
    float dd[4] = { dv.x, dv.y, dv.z, dv.w };
    float s = 0.f;
    u16 o16[4];
#pragma unroll
    for (int j = 0; j < 4; ++j) {
        float as = (vv[j] >= kth) ? vv[j] : 0.f;
        float a = fmaxf(as + dd[j], 0.f);
        o16[j] = f2b(a);
        s += a;
    }
    uint2 ow;
    ow.x = (unsigned)o16[0] | ((unsigned)o16[1] << 16);
    ow.y = (unsigned)o16[2] | ((unsigned)o16[3] << 16);
    bA2[(size_t)row * 64 + lane] = ow;
#pragma unroll
    for (int o = 32; o > 0; o >>= 1) s += __shfl_down(s, o, 64);
    if (lane == 0) dinv[row] = rsqrtf(s + EPSD);
}

// ---------------- fused BN-apply + full Chebyshev recursion (Tx0, Tx1, Tx2) ----------------
// Block = (t-slice of 128 cols, batch). 512 threads / 8 waves (4 row-groups x 2 col-groups).
// Zt[128 t][256 m] bf16 stays LDS-resident; A streamed twice with double-buffered DMA.
__global__ __launch_bounds__(512) void cheb_fused_k(const uint2* __restrict__ xhi,
                                                    const uint2* __restrict__ xlo,
                                                    const float* __restrict__ bnacc,
                                                    const float* __restrict__ g,
                                                    const float* __restrict__ be,
                                                    const float* __restrict__ dinv,
                                                    const u16* __restrict__ bA,
                                                    u16* __restrict__ cat) {
    __shared__ u16 Zt[128 * 256];          // 64KB  [t][m-chunk swizzled]
    __shared__ u16 As[2][2][256 * 32];     // 64KB  [buf][half][row*32 + chunk]
    __shared__ float scl[256], sft[256], dvv[256];
    int z = blockIdx.y, tb = blockIdx.x;   // tb in [0,4): 128-col t-slice
    int tid = threadIdx.x, lane = tid & 63, wave = tid >> 6;
    const u16* Ab = bA + (size_t)z * (Nn * Nn);
    int wr = (wave >> 1) * 64, wc = (wave & 1) * 64;
    int fr = lane & 15, fq = lane >> 4;

    // phase 0: per-node BN scale/shift + dinv into LDS
    if (tid < 256) {
        const float inv = 1.f / (Bb * Td);
        float s = bnacc[2 * tid], s2 = bnacc[2 * tid + 1];
        float mu = s * inv;
        float var = s2 * inv - mu * mu;
        float rs = rsqrtf(var + EPSN);
        float sc_ = rs * g[tid];
        scl[tid] = sc_;
        sft[tid] = be[tid] - mu * sc_;
        dvv[tid] = dinv[z * 256 + tid];
    }
    __syncthreads();

    auto stageA = [&](int buf, int k0) {
#pragma unroll
        for (int h = 0; h < 2; ++h) {
#pragma unroll
            for (int sub = 0; sub < 2; ++sub) {
                int r = wave * 32 + sub * 16 + (lane >> 2);
                int kc = ((lane & 3) ^ swz4(r)) << 3;
                gload_lds(Ab + (size_t)r * 256 + k0 + h * 32 + kc,
                          &As[buf][h][(wave * 32 + sub * 16) * 32]);
            }
        }
    };

    f32x4 acc[4][4] = {};
    auto compute = [&](int buf, int kk) {
#pragma unroll
        for (int h = 0; h < 2; ++h) {
            short8 af[4], bf[4];
#pragma unroll
            for (int mi = 0; mi < 4; ++mi) {
                int rr = wr + mi * 16 + fr;
                af[mi] = *(const short8*)&As[buf][h][rr * 32 + ((fq ^ swz4(rr)) << 3)];
            }
            int c5 = ((kk + h * 32) >> 3) + fq;
#pragma unroll
            for (int ni = 0; ni < 4; ++ni) {
                int cc = wc + ni * 16 + fr;
                bf[ni] = *(const short8*)&Zt[cc * 256 + ((c5 ^ (cc & 31)) << 3)];
            }
#pragma unroll
            for (int mi = 0; mi < 4; ++mi)
#pragma unroll
                for (int ni = 0; ni < 4; ++ni)
                    acc[mi][ni] = __builtin_amdgcn_mfma_f32_16x16x32_bf16(af[mi], bf[ni], acc[mi][ni], 0, 0, 0);
        }
    };

    // issue GEMM1 step-0 DMA; it lands during Z-build
    stageA(0, 0);

    // Z-build: BN apply -> write cat Tx0 (global) + Z0 = dv*Tx0 (LDS, transposed)
    {
        int mrow = tid >> 5;            // 16 rows per pass
        int c = tid & 31;               // uint2 col within 32 (4 t each)
        int t4g0 = tb * 32;
#pragma unroll 4
        for (int p = 0; p < 16; ++p) {
            int m = p * 16 + mrow;
            size_t idx = ((size_t)(z * 256 + m)) * 128 + t4g0 + c;
            float4 v = unp2(xhi[idx], xlo[idx]);
            float sc_ = scl[m], sh_ = sft[m], dv = dvv[m];
            v.x = v.x * sc_ + sh_; v.y = v.y * sc_ + sh_;
            v.z = v.z * sc_ + sh_; v.w = v.w * sc_ + sh_;
            uint2 o2;
            o2.x = (unsigned)f2b(v.x) | ((unsigned)f2b(v.y) << 16);
            o2.y = (unsigned)f2b(v.z) | ((unsigned)f2b(v.w) << 16);
            *(uint2*)&cat[((size_t)(z * 256 + m)) * 1536 + (size_t)(t4g0 + c) * 4] = o2;
            u16 zv[4] = { f2b(v.x * dv), f2b(v.y * dv), f2b(v.z * dv), f2b(v.w * dv) };
#pragma unroll
            for (int j = 0; j < 4; ++j) {
                int tl = c * 4 + j;     // local t in [0,128)
                Zt[tl * 256 + (((m >> 3) ^ (tl & 31)) << 3) + (m & 7)] = zv[j];
            }
        }
    }
    __syncthreads();   // Z0 visible + GEMM1 step-0 DMA drained

    // GEMM1: Y1 = A @ Z0   (K=256, 4 steps of 64)
    for (int s = 0; s < 4; ++s) {
        if (s < 3) stageA((s + 1) & 1, (s + 1) * 64);
        compute(s & 1, s * 64);
        __syncthreads();
    }

    // prefetch GEMM2 step-0 (overlaps epilogue-1)
    stageA(0, 0);

    // epilogue 1: Tx1 = dv[n]*Y1 -> cat[.,512:1024]; Z1 = dv[n]*Tx1 -> Zt
#pragma unroll
    for (int mi = 0; mi < 4; ++mi) {
#pragma unroll
        for (int rg = 0; rg < 4; ++rg) {
            int n = wr + mi * 16 + fq * 4 + rg;
            float dv = dvv[n];
            size_t rowb = (size_t)(z * 256 + n) * 1536;
#pragma unroll
            for (int ni = 0; ni < 4; ++ni) {
                int tl = wc + ni * 16 + fr;
                float tx1 = dv * acc[mi][ni][rg];
                cat[rowb + 512 + tb * 128 + tl] = f2b(tx1);
                Zt[tl * 256 + (((n >> 3) ^ (tl & 31)) << 3) + (n & 7)] = f2b(dv * tx1);
            }
            acc[mi][0][rg] = 0.f; acc[mi][1][rg] = 0.f;
            acc[mi][2][rg] = 0.f; acc[mi][3][rg] = 0.f;
        }
    }
    __syncthreads();   // Z1 visible + GEMM2 step-0 DMA drained

    // GEMM2: Y2 = A @ Z1
    for (int s = 0; s < 4; ++s) {
        if (s < 3) stageA((s + 1) & 1, (s + 1) * 64);
        compute(s & 1, s * 64);
        if (s < 3) __syncthreads();
    }

    // epilogue 2: Tx2 = 2*dv[n]*Y2 - Tx0 -> cat[.,1024:1536]  (Tx0 read back, L2-hot)
    __threadfence_block();
#pragma unroll
    for (int mi = 0; mi < 4; ++mi) {
#pragma unroll
        for (int rg = 0; rg < 4; ++rg) {
            int n = wr + mi * 16 + fq * 4 + rg;
            float dv2 = 2.f * dvv[n];
            size_t rowb = (size_t)(z * 256 + n) * 1536;
#pragma unroll
            for (int ni = 0; ni < 4; ++ni) {
                int tg = tb * 128 + wc + ni * 16 + fr;
                float v = dv2 * acc[mi][ni][rg] - b2f(cat[rowb + tg]);
                cat[rowb + 1024 + tg] = f2b(v);
            }
        }
    }
}

// ---------------- bf16 MFMA GEMM, NT, DMA + double-buffered prefetch, BK=64 ----------------
// R2-measured-best config for the final K=1536 gemm (40.4 us). Do not re-tile:
// BK=32 (R5), 4-buf counted-vmcnt (R6), 64x128 (R7) all measured equal-or-worse.
template <bool FINAL, bool WF32>
__global__ __launch_bounds__(256) void gemm_bf_k(const u16* __restrict__ A,
                                                 const u16* __restrict__ Bt,
                                                 const float* __restrict__ bias,
                                                 float* __restrict__ C,
                                                 int Ncols, int K) {
    __shared__ u16 As[2][8192];   // [buf][h*4096 + row*32 + swizzled chunk]
    __shared__ u16 Bs[2][8192];
    const u16* Ag = A;
    const u16* Bg = Bt;
    int br = blockIdx.x * 128, bc = blockIdx.y * 128;
    int tid = threadIdx.x, lane = tid & 63, wave = tid >> 6;
    int wr = (wave >> 1) * 64, wc = (wave & 1) * 64;
    int i0 = wave * 2;
    int rl0 = i0 * 16 + (lane >> 2);
    int rl1 = rl0 + 16;
    int cp = lane & 3;
    int ca0 = (cp ^ swz4(rl0)) * 8;
    int ca1 = (cp ^ swz4(rl1)) * 8;
    const u16* gA0 = Ag + (size_t)(br + rl0) * K + ca0;
    const u16* gA1 = Ag + (size_t)(br + rl1) * K + ca1;
    const u16* gB0 = Bg + (size_t)(bc + rl0) * K + ca0;
    const u16* gB1 = Bg + (size_t)(bc + rl1) * K + ca1;
    f32x4 acc[4][4] = {};
    int fr = lane & 15, fq = lane >> 4;
    auto stage = [&](int buf, int k0) {
#pragma unroll
        for (int h = 0; h < 2; ++h) {
            int kk = k0 + h * 32;
            int ho = h * 4096;
            gload_lds(gA0 + kk, &As[buf][ho + i0 * 512]);
            gload_lds(gA1 + kk, &As[buf][ho + i0 * 512 + 512]);
            gload_lds(gB0 + kk, &Bs[buf][ho + i0 * 512]);
            gload_lds(gB1 + kk, &Bs[buf][ho + i0 * 512 + 512]);
        }
    };
    int nIter = K >> 6;
    stage(0, 0);
    for (int it = 0; it < nIter; ++it) {
        int cur = it & 1;
        __syncthreads();                       // drains stage(cur) issued one iter ago
        if (it + 1 < nIter) stage(1 - cur, (it + 1) << 6);
#pragma unroll
        for (int h = 0; h < 2; ++h) {
            int ho = h * 4096;
            short8 af[4], bf[4];
#pragma unroll
            for (int mi = 0; mi < 4; ++mi) {
                int rr = wr + mi * 16 + fr;
                af[mi] = *(const short8*)&As[cur][ho + rr * 32 + ((fq ^ swz4(rr)) << 3)];
            }
#pragma unroll
            for (int ni = 0; ni < 4; ++ni) {
                int rr = wc + ni * 16 + fr;
                bf[ni] = *(const short8*)&Bs[cur][ho + rr * 32 + ((fq ^ swz4(rr)) << 3)];
            }
#pragma unroll
            for (int mi = 0; mi < 4; ++mi)
#pragma unroll
                for (int ni = 0; ni < 4; ++ni)
                    acc[mi][ni] = __builtin_amdgcn_mfma_f32_16x16x32_bf16(af[mi], bf[ni], acc[mi][ni], 0, 0, 0);
        }
    }
#pragma unroll
    for (int mi = 0; mi < 4; ++mi) {
#pragma unroll
        for (int rg = 0; rg < 4; ++rg) {
            int row = br + wr + mi * 16 + fq * 4 + rg;
#pragma unroll
            for (int ni = 0; ni < 4; ++ni) {
                int col = bc + wc + ni * 16 + fr;
                float v = acc[mi][ni][rg];
                if (FINAL) v = fmaxf(v + bias[col], 0.f);
                if (WF32) C[(size_t)row * Ncols + col] = v;
            }
        }
    }
}

// ---------------- split-bf16 3-MFMA GEMM, NT, DMA + double-buffered prefetch, BK=32 ----------------
// 128x128 tile (measured best; NB=64 variant cost +5us in R4/R8 A/B).
template <bool BIAS, bool WSPLIT, bool WF32>
__global__ __launch_bounds__(256) void gemm_bf3_k(const u16* __restrict__ Ahi,
                                                  const u16* __restrict__ Alo,
                                                  const u16* __restrict__ Bhi,
                                                  const u16* __restrict__ Blo,
                                                  const float* __restrict__ bias,
                                                  float* __restrict__ C,
                                                  u16* __restrict__ Chi,
                                                  u16* __restrict__ Clo,
                                                  int Ncols, int K,
                                                  long long sA, long long sB, long long sC) {
    __shared__ u16 Ash[2][4096];
    __shared__ u16 Asl[2][4096];
    __shared__ u16 Bsh[2][4096];
    __shared__ u16 Bsl[2][4096];
    int z = blockIdx.z;
    const u16* Agh = Ahi + (size_t)z * sA;
    const u16* Agl = Alo + (size_t)z * sA;
    const u16* Bgh = Bhi + (size_t)z * sB;
    const u16* Bgl = Blo + (size_t)z * sB;
    int br = blockIdx.x * 128, bc = blockIdx.y * 128;
    int tid = threadIdx.x, lane = tid & 63, wave = tid >> 6;
    int wr = (wave >> 1) * 64, wc = (wave & 1) * 64;
    int i0 = wave * 2;
    int rl0 = i0 * 16 + (lane >> 2);
    int rl1 = rl0 + 16;
    int cp = lane & 3;
    int ca0 = (cp ^ swz4(rl0)) * 8;
    int ca1 = (cp ^ swz4(rl1)) * 8;
    size_t oA0 = (size_t)(br + rl0) * K + ca0;
    size_t oA1 = (size_t)(br + rl1) * K + ca1;
    size_t oB0 = (size_t)(bc + rl0) * K + ca0;
    size_t oB1 = (size_t)(bc + rl1) * K + ca1;
    f32x4 acc[4][4] = {};
    int fr = lane & 15, fq = lane >> 4;
    auto stage = [&](int buf, int kk) {
        gload_lds(Agh + oA0 + kk, &Ash[buf][i0 * 512]);
        gload_lds(Agh + oA1 + kk, &Ash[buf][i0 * 512 + 512]);
        gload_lds(Agl + oA0 + kk, &Asl[buf][i0 * 512]);
        gload_lds(Agl + oA1 + kk, &Asl[buf][i0 * 512 + 512]);
        gload_lds(Bgh + oB0 + kk, &Bsh[buf][i0 * 512]);
        gload_lds(Bgh + oB1 + kk, &Bsh[buf][i0 * 512 + 512]);
        gload_lds(Bgl + oB0 + kk, &Bsl[buf][i0 * 512]);
        gload_lds(Bgl + oB1 + kk, &Bsl[buf][i0 * 512 + 512]);
    };
    int nIter = K >> 5;
    stage(0, 0);
    for (int it = 0; it < nIter; ++it) {
        int cur = it & 1;
        __syncthreads();
        if (it + 1 < nIter) stage(1 - cur, (it + 1) << 5);
        short8 afh[4], afl[4], bfh[4], bfl[4];
#pragma unroll
        for (int mi = 0; mi < 4; ++mi) {
            int rr = wr + mi * 16 + fr;
            int off = rr * 32 + ((fq ^ swz4(rr)) << 3);
            afh[mi] = *(const short8*)&Ash[cur][off];
            afl[mi] = *(const short8*)&Asl[cur][off];
        }
#pragma unroll
        for (int ni = 0; ni < 4; ++ni) {
            int rr = wc + ni * 16 + fr;
            int off = rr * 32 + ((fq ^ swz4(rr)) << 3);
            bfh[ni] = *(const short8*)&Bsh[cur][off];
            bfl[ni] = *(const short8*)&Bsl[cur][off];
        }
#pragma unroll
        for (int mi = 0; mi < 4; ++mi)
#pragma unroll
            for (int ni = 0; ni < 4; ++ni) {
                acc[mi][ni] = __builtin_amdgcn_mfma_f32_16x16x32_bf16(afh[mi], bfh[ni], acc[mi][ni], 0, 0, 0);
                acc[mi][ni] = __builtin_amdgcn_mfma_f32_16x16x32_bf16(afh[mi], bfl[ni], acc[mi][ni], 0, 0, 0);
                acc[mi][ni] = __builtin_amdgcn_mfma_f32_16x16x32_bf16(afl[mi], bfh[ni], acc[mi][ni], 0, 0, 0);
            }
    }
    float* Cp = WF32 ? C + (size_t)z * sC : nullptr;
    u16* Chp = WSPLIT ? Chi + (size_t)z * sC : nullptr;
    u16* Clp = WSPLIT ? Clo + (size_t)z * sC : nullptr;
#pragma unroll
    for (int mi = 0; mi < 4; ++mi) {
#pragma unroll
        for (int rg = 0; rg < 4; ++rg) {
            int row = br + wr + mi * 16 + fq * 4 + rg;
            size_t rb = (size_t)row * Ncols;
#pragma unroll
            for (int ni = 0; ni < 4; ++ni) {
                int col = bc + wc + ni * 16 + fr;
                float v = acc[mi][ni][rg];
                if (BIAS) v += bias[col];
                if (WF32) Cp[rb + col] = v;
                if (WSPLIT) {
                    u16 h = f2b(v);
                    Chp[rb + col] = h;
                    Clp[rb + col] = f2b(v - b2f(h));
                }
            }
        }
    }
}

extern "C" void kernel_launch(void* const* d_in, const int* in_sizes, int n_in,
                              void* d_out, int out_size, void* d_ws, size_t ws_size,
                              hipStream_t stream) {
    const float* x      = (const float*)d_in[0];
    const float* dis    = (const float*)d_in[1];
    const float* ln_w   = (const float*)d_in[2];
    const float* ln_b   = (const float*)d_in[3];
    const float* bn_g   = (const float*)d_in[4];
    const float* bn_b   = (const float*)d_in[5];
    const float* li_w   = (const float*)d_in[6];
    const float* li_b   = (const float*)d_in[7];
    const float* cheb_w = (const float*)d_in[8];
    const float* cheb_b = (const float*)d_in[9];
    float* out = (float*)d_out;

    const size_t BNT = (size_t)Bb * Nn * Td;   // 8388608
    const size_t BNN = (size_t)Bb * Nn * Nn;   // 4194304
    float* ws = (float*)d_ws;
    u16* xhi = (u16*)ws;
    u16* xlo = xhi + BNT;
    u16* xphi = (u16*)(ws + BNT);
    u16* xplo = xphi + BNT;
    u16* cat  = (u16*)(ws + BNT);               // [16384][1536] bf16 (reuses xp region after scores)
    float* sc = ws + 2 * BNT;
    float* p4 = ws + 2 * BNT + BNN;
    float* p5 = p4 + BNT / 2;
    u16* bA = (u16*)p5;                          // BNN u16
    float* p6 = p5 + BNN / 2;
    u16* bWc = (u16*)p6;                         // 512*1536 u16
    float* p7 = p6 + (512 * 1536) / 2;
    u16* liwhi = (u16*)p7;                       // 512*512 u16 x2
    u16* liwlo = liwhi + 512 * 512;
    float* p8 = p7 + 262144;
    float* dinv = p8;                            // 16384
    float2* part = (float2*)(dinv + 16384);      // 2048 float2
    float* bnacc = (float*)(part + 2048);        // 512 floats (BN sum/sumsq accum)

    // 1. LN stage A + param prep + bnacc zero (one launch, grid-z split)
    hipLaunchKernelGGL(prep_ln_partial_k, dim3(32, Bb, 2), dim3(256), 0, stream,
                       (const float4*)x, part, cheb_w, bWc, li_w, liwhi, liwlo, bnacc);
    // 2. LN apply (block-wide finalize broadcast) -> hi/lo split; BN stats via atomics
    hipLaunchKernelGGL(ln_apply_split_k, dim3(BNT / 16384), dim3(1024), 0, stream,
                       (const float4*)x, (const float4*)ln_w, (const float4*)ln_b, part,
                       (uint2*)xhi, (uint2*)xlo, bnacc);
    // 3. xp = x_ln @ li_w^T + li_b  (split-bf16 3-MFMA -> hi/lo)
    hipLaunchKernelGGL((gemm_bf3_k<true, true, false>), dim3(Bb * Nn / 128, Td / 128, 1), dim3(256), 0, stream,
                       xhi, xlo, liwhi, liwlo, li_b, (float*)nullptr, xphi, xplo,
                       Td, Td, 0LL, 0LL, 0LL);
    // 4. scores[b] = xp[b] @ xp[b]^T  (split-bf16 -> fp32)
    hipLaunchKernelGGL((gemm_bf3_k<false, false, true>), dim3(Nn / 128, Nn / 128, Bb), dim3(256), 0, stream,
                       xphi, xplo, xphi, xplo, (const float*)nullptr, sc, (u16*)nullptr, (u16*)nullptr,
                       Nn, Td, (long long)Nn * Td, (long long)Nn * Td, (long long)Nn * Nn);
    // 5. top-k wave-per-row radix select; A = relu(A_s + dis) -> bf16 bA; dinv
    hipLaunchKernelGGL(topk_sel_k, dim3(Bb * Nn / 4), dim3(256), 0, stream,
                       (const float4*)sc, (const float4*)dis, (uint2*)bA, dinv);
    // 6. fused BN-apply + Chebyshev (512 thr / 8 waves): writes cat Tx0|Tx1|Tx2
    hipLaunchKernelGGL(cheb_fused_k, dim3(Td / 128, Bb), dim3(512), 0, stream,
                       (const uint2*)xhi, (const uint2*)xlo, bnacc, bn_g, bn_b,
                       dinv, bA, cat);
    // 7. out = relu([Tx0|Tx1|Tx2] @ [W0;W1;W2]^T + cheb_b)  (K=1536, R2-best 128^2 BK=64)
    hipLaunchKernelGGL((gemm_bf_k<true, true>), dim3(Bb * Nn / 128, Td / 128, 1), dim3(256), 0, stream,
                       cat, bWc, cheb_b, out, Td, 1536);
}